// Round 1
// baseline (4354.135 us; speedup 1.0000x reference)
//
#include <hip/hip_runtime.h>
#include <cstdint>
#include <cstddef>

// Problem constants
#define BSZ 16
#define T   8192
#define CDIM 256
#define HDIM 256
#define KW  7

constexpr int BT = BSZ * T;                  // 131072
constexpr float TAU = 2e-3f;                 // f64 recheck band for |d|
constexpr int UCAP = 32768;

// workspace layout in float units
constexpr size_t OFF_W1T = 0;                          // 7*256*256 = 458752
constexpr size_t OFF_W2T = OFF_W1T + 458752;           // 3*256*256 = 196608
constexpr size_t OFF_V   = OFF_W2T + 196608;           // 256
constexpr size_t OFF_D   = OFF_V + 256;                // BT floats
constexpr size_t OFF_ISB = OFF_D + BT;                 // BT ints
constexpr size_t OFF_SID = OFF_ISB + BT;               // BT ints
constexpr size_t OFF_SST = OFF_SID + BT;               // BT ints
constexpr size_t OFF_SEN = OFF_SST + BT;               // BT ints
constexpr size_t OFF_NV  = OFF_SEN + BT;               // BSZ ints
constexpr size_t OFF_UCT = OFF_NV + BSZ;               // 1 int
constexpr size_t OFF_UL  = OFF_UCT + 1;                // UCAP ints

// ---------------- repack weights ----------------
// W1T[k][c][h] = w1[h][c][k]; W2T[k][hin][hout] = w2[hout][hin][k]; v[h]=w3[1,h]-w3[0,h]
__global__ void repack_kernel(const float* __restrict__ w1, const float* __restrict__ w2,
                              const float* __restrict__ w3,
                              float* __restrict__ W1T, float* __restrict__ W2T,
                              float* __restrict__ v)
{
    int idx = blockIdx.x * blockDim.x + threadIdx.x;
    int stride = gridDim.x * blockDim.x;
    for (int i = idx; i < KW * CDIM * HDIM; i += stride) {
        int k = i / (CDIM * HDIM);
        int c = (i / HDIM) % CDIM;
        int h = i % HDIM;
        W1T[i] = w1[(size_t)h * (CDIM * KW) + c * KW + k];
    }
    for (int i = idx; i < 3 * HDIM * HDIM; i += stride) {
        int k = i / (HDIM * HDIM);
        int c = (i / HDIM) % HDIM;
        int h = i % HDIM;
        W2T[i] = w2[(size_t)h * (HDIM * 3) + c * 3 + k];
    }
    if (idx < HDIM) v[idx] = w3[HDIM + idx] - w3[idx];
}

// ---------------- conv1: h1 = relu(conv(x, w1, pad=3)) ----------------
// block: 64 tokens x 64 h, 256 threads (16x16), 4x4 register tile
__global__ __launch_bounds__(256) void conv1_kernel(
    const float* __restrict__ x, const float* __restrict__ W1T,
    const float* __restrict__ b1, float* __restrict__ h1)
{
    __shared__ float Xs[70][17];
    __shared__ float Ws[7][16][64];
    const int tid = threadIdx.x;
    const int b  = blockIdx.x >> 7;            // T/64 = 128 token-blocks per batch
    const int t0 = (blockIdx.x & 127) << 6;
    const int h0 = blockIdx.y << 6;
    const int tx = tid & 15, ty = tid >> 4;

    float acc[4][4] = {};
    for (int c0 = 0; c0 < CDIM; c0 += 16) {
        {   // stage x window (70 rows x 16 c), zero-pad time edges
            int cc = tid & 15, rb = tid >> 4;
            #pragma unroll
            for (int j = 0; j < 5; ++j) {
                int r = rb + 16 * j;
                if (r < 70) {
                    int t = t0 + r - 3;
                    float val = 0.f;
                    if (t >= 0 && t < T) val = x[(size_t)(b * T + t) * CDIM + c0 + cc];
                    Xs[r][cc] = val;
                }
            }
        }
        {   // stage weights: 7*16*64 = 7168
            int hh = tid & 63, q = tid >> 6;
            #pragma unroll
            for (int j = 0; j < 28; ++j) {
                int lin = q * 28 + j;          // 0..111 = (k,cc)
                int k = lin >> 4, cc = lin & 15;
                Ws[k][cc][hh] = W1T[(size_t)k * 65536 + (size_t)(c0 + cc) * 256 + h0 + hh];
            }
        }
        __syncthreads();
        for (int k = 0; k < KW; ++k) {
            #pragma unroll
            for (int cc = 0; cc < 16; ++cc) {
                float a0 = Xs[ty * 4 + 0 + k][cc];
                float a1 = Xs[ty * 4 + 1 + k][cc];
                float a2 = Xs[ty * 4 + 2 + k][cc];
                float a3 = Xs[ty * 4 + 3 + k][cc];
                const float4 bv = *(const float4*)&Ws[k][cc][tx * 4];
                acc[0][0] += a0 * bv.x; acc[0][1] += a0 * bv.y; acc[0][2] += a0 * bv.z; acc[0][3] += a0 * bv.w;
                acc[1][0] += a1 * bv.x; acc[1][1] += a1 * bv.y; acc[1][2] += a1 * bv.z; acc[1][3] += a1 * bv.w;
                acc[2][0] += a2 * bv.x; acc[2][1] += a2 * bv.y; acc[2][2] += a2 * bv.z; acc[2][3] += a2 * bv.w;
                acc[3][0] += a3 * bv.x; acc[3][1] += a3 * bv.y; acc[3][2] += a3 * bv.z; acc[3][3] += a3 * bv.w;
            }
        }
        __syncthreads();
    }
    const float4 bb = *(const float4*)&b1[h0 + tx * 4];
    #pragma unroll
    for (int r = 0; r < 4; ++r) {
        float4 o;
        o.x = fmaxf(acc[r][0] + bb.x, 0.f);
        o.y = fmaxf(acc[r][1] + bb.y, 0.f);
        o.z = fmaxf(acc[r][2] + bb.z, 0.f);
        o.w = fmaxf(acc[r][3] + bb.w, 0.f);
        *(float4*)&h1[(size_t)(b * T + t0 + ty * 4 + r) * HDIM + h0 + tx * 4] = o;
    }
}

// ---------------- conv2 fused with 1x1 score: d[t] += sum_h v[h]*relu(conv2(h1))[t,h] ----------------
__global__ __launch_bounds__(256) void conv2_kernel(
    const float* __restrict__ h1, const float* __restrict__ W2T,
    const float* __restrict__ b2, const float* __restrict__ v,
    float* __restrict__ d)
{
    __shared__ float Xs[66][17];
    __shared__ float Ws[3][16][64];
    __shared__ float red[64][16];
    const int tid = threadIdx.x;
    const int b  = blockIdx.x >> 7;
    const int t0 = (blockIdx.x & 127) << 6;
    const int h0 = blockIdx.y << 6;
    const int tx = tid & 15, ty = tid >> 4;

    float acc[4][4] = {};
    for (int c0 = 0; c0 < HDIM; c0 += 16) {
        {
            int cc = tid & 15, rb = tid >> 4;
            #pragma unroll
            for (int j = 0; j < 5; ++j) {
                int r = rb + 16 * j;
                if (r < 66) {
                    int t = t0 + r - 1;
                    float val = 0.f;
                    if (t >= 0 && t < T) val = h1[(size_t)(b * T + t) * HDIM + c0 + cc];
                    Xs[r][cc] = val;
                }
            }
        }
        {
            int hh = tid & 63, q = tid >> 6;
            #pragma unroll
            for (int j = 0; j < 12; ++j) {
                int lin = q * 12 + j;          // 0..47 = (k,cc)
                int k = lin >> 4, cc = lin & 15;
                Ws[k][cc][hh] = W2T[(size_t)k * 65536 + (size_t)(c0 + cc) * 256 + h0 + hh];
            }
        }
        __syncthreads();
        for (int k = 0; k < 3; ++k) {
            #pragma unroll
            for (int cc = 0; cc < 16; ++cc) {
                float a0 = Xs[ty * 4 + 0 + k][cc];
                float a1 = Xs[ty * 4 + 1 + k][cc];
                float a2 = Xs[ty * 4 + 2 + k][cc];
                float a3 = Xs[ty * 4 + 3 + k][cc];
                const float4 bv = *(const float4*)&Ws[k][cc][tx * 4];
                acc[0][0] += a0 * bv.x; acc[0][1] += a0 * bv.y; acc[0][2] += a0 * bv.z; acc[0][3] += a0 * bv.w;
                acc[1][0] += a1 * bv.x; acc[1][1] += a1 * bv.y; acc[1][2] += a1 * bv.z; acc[1][3] += a1 * bv.w;
                acc[2][0] += a2 * bv.x; acc[2][1] += a2 * bv.y; acc[2][2] += a2 * bv.z; acc[2][3] += a2 * bv.w;
                acc[3][0] += a3 * bv.x; acc[3][1] += a3 * bv.y; acc[3][2] += a3 * bv.z; acc[3][3] += a3 * bv.w;
            }
        }
        __syncthreads();
    }
    const float4 b2v = *(const float4*)&b2[h0 + tx * 4];
    const float4 vv  = *(const float4*)&v[h0 + tx * 4];
    #pragma unroll
    for (int r = 0; r < 4; ++r) {
        float p = fmaxf(acc[r][0] + b2v.x, 0.f) * vv.x
                + fmaxf(acc[r][1] + b2v.y, 0.f) * vv.y
                + fmaxf(acc[r][2] + b2v.z, 0.f) * vv.z
                + fmaxf(acc[r][3] + b2v.w, 0.f) * vv.w;
        red[ty * 4 + r][tx] = p;
    }
    __syncthreads();
    if (tid < 64) {
        float s = 0.f;
        #pragma unroll
        for (int j = 0; j < 16; ++j) s += red[tid][j];
        atomicAdd(&d[b * T + t0 + tid], s);
    }
}

// ---------------- boundary bit + uncertainty list ----------------
__global__ void boundary_kernel(const float* __restrict__ d, const int* __restrict__ padmask,
                                const float* __restrict__ b3,
                                int* __restrict__ isb, int* __restrict__ ucount,
                                int* __restrict__ ulist)
{
    int bt = blockIdx.x * 256 + threadIdx.x;
    if (bt >= BT) return;
    int pad = padmask[bt];
    float dd = d[bt] + (b3[1] - b3[0]);
    isb[bt] = (pad == 0 && dd > 0.f) ? 1 : 0;
    if (pad == 0 && fabsf(dd) < TAU) {
        int slot = atomicAdd(ucount, 1);
        if (slot < UCAP) ulist[slot] = bt;
    }
}

// ---------------- exact f64 recheck of near-tie tokens ----------------
__global__ __launch_bounds__(256) void recheck_kernel(
    const float* __restrict__ x, const float* __restrict__ W1T,
    const float* __restrict__ W2T, const float* __restrict__ b1,
    const float* __restrict__ b2, const float* __restrict__ w3,
    const float* __restrict__ b3,
    const int* __restrict__ ulist, const int* __restrict__ ucount,
    int* __restrict__ isb)
{
    __shared__ double h1s[3][HDIM];
    __shared__ double red[HDIM];
    int n = *ucount; if (n > UCAP) n = UCAP;
    const int h = threadIdx.x;
    for (int li = blockIdx.x; li < n; li += gridDim.x) {
        int bt = ulist[li];
        int b = bt >> 13, t = bt & (T - 1);
        #pragma unroll
        for (int dt = -1; dt <= 1; ++dt) {
            double acc = (double)b1[h];
            int tc = t + dt;
            if (tc >= 0 && tc < T) {
                for (int k = 0; k < KW; ++k) {
                    int tt = tc + k - 3;
                    if (tt < 0 || tt >= T) continue;
                    const float* xrow = &x[(size_t)(b * T + tt) * CDIM];
                    const float* wrow = &W1T[(size_t)k * 65536 + h];
                    for (int c = 0; c < CDIM; ++c)
                        acc += (double)xrow[c] * (double)wrow[(size_t)c * 256];
                }
            }
            h1s[dt + 1][h] = acc > 0.0 ? acc : 0.0;
        }
        __syncthreads();
        double acc2 = (double)b2[h];
        for (int k = 0; k < 3; ++k) {
            int tt = t + k - 1;
            if (tt < 0 || tt >= T) continue;
            const double* hrow = h1s[k];
            const float* wrow = &W2T[(size_t)k * 65536 + h];
            for (int c = 0; c < HDIM; ++c)
                acc2 += hrow[c] * (double)wrow[(size_t)c * 256];
        }
        double h2v = acc2 > 0.0 ? acc2 : 0.0;
        double vd = (double)w3[HDIM + h] - (double)w3[h];
        red[h] = vd * h2v;
        __syncthreads();
        for (int off = 128; off > 0; off >>= 1) {
            if (h < off) red[h] += red[h + off];
            __syncthreads();
        }
        if (h == 0) {
            double dd = red[0] + ((double)b3[1] - (double)b3[0]);
            isb[bt] = (dd > 0.0) ? 1 : 0;
        }
        __syncthreads();
    }
}

// ---------------- per-batch inclusive cumsum -> seg_id, n_valid ----------------
__global__ __launch_bounds__(1024) void scan_kernel(
    const int* __restrict__ isb, const int* __restrict__ padmask,
    int* __restrict__ sid, int* __restrict__ nvalid)
{
    __shared__ int ssum[1024];
    const int b = blockIdx.x, tid = threadIdx.x;
    const int base = b * T;
    int vals[8]; int s = 0;
    #pragma unroll
    for (int i = 0; i < 8; ++i) { vals[i] = isb[base + tid * 8 + i]; s += vals[i]; }
    ssum[tid] = s;
    __syncthreads();
    for (int off = 1; off < 1024; off <<= 1) {
        int add = (tid >= off) ? ssum[tid - off] : 0;
        __syncthreads();
        ssum[tid] += add;
        __syncthreads();
    }
    int run = ssum[tid] - s;   // exclusive prefix
    #pragma unroll
    for (int i = 0; i < 8; ++i) {
        int t = tid * 8 + i;
        run += vals[i];
        sid[base + t] = (padmask[base + t] != 0) ? T : run;
    }
    if (tid == 1023) {
        int nb = ssum[1023];
        nvalid[b] = (padmask[base] == 0) ? (nb + 1) : 0;
    }
}

// ---------------- segment range extraction (no atomics: unique writers) ----------------
__global__ void segbounds_kernel(const int* __restrict__ sid, const int* __restrict__ padmask,
                                 int* __restrict__ sst, int* __restrict__ sen)
{
    int bt = blockIdx.x * 256 + threadIdx.x;
    if (bt >= BT) return;
    if (padmask[bt] != 0) return;
    int t = bt & (T - 1);
    int b = bt >> 13;
    int s = sid[bt];
    if (t == 0) {
        if (s < T) sst[b * T + s] = 0;
    } else if (s != sid[bt - 1]) {
        if (s < T) sst[b * T + s] = t;
    }
    bool last = (t == T - 1) || (padmask[bt + 1] != 0);
    if (s < T && (last || sid[bt + 1] != s)) sen[b * T + s] = t + 1;
}

// ---------------- segment-mean pooling + new_pad ----------------
__global__ __launch_bounds__(256) void pool_kernel(
    const float* __restrict__ x, const int* __restrict__ sst,
    const int* __restrict__ sen, const int* __restrict__ nvalid,
    float* __restrict__ out)
{
    int slot = blockIdx.x * 4 + (threadIdx.x >> 6);   // = b*T + s
    int lane = threadIdx.x & 63;
    int b = slot >> 13;
    int s = slot & (T - 1);
    int nv = nvalid[b];
    float4 res = make_float4(0.f, 0.f, 0.f, 0.f);
    if (s < nv) {
        int st = sst[slot], en = sen[slot];
        if (st >= 0 && en > st) {
            float4 a = make_float4(0.f, 0.f, 0.f, 0.f);
            const float* xp = &x[(size_t)(b * T + st) * CDIM + lane * 4];
            for (int t = st; t < en; ++t) {
                float4 xv = *(const float4*)xp;
                a.x += xv.x; a.y += xv.y; a.z += xv.z; a.w += xv.w;
                xp += CDIM;
            }
            float inv = 1.f / (float)(en - st);
            res = make_float4(a.x * inv, a.y * inv, a.z * inv, a.w * inv);
        }
    }
    *(float4*)&out[(size_t)slot * CDIM + lane * 4] = res;
    if (lane == 0) out[(size_t)BT * CDIM + slot] = (s < nv) ? 0.f : 1.f;
}

extern "C" void kernel_launch(void* const* d_in, const int* in_sizes, int n_in,
                              void* d_out, int out_size, void* d_ws, size_t ws_size,
                              hipStream_t stream)
{
    const float* x  = (const float*)d_in[0];
    const int* padmask = (const int*)d_in[1];   // bool mask; test != 0 (robust to i32/f32 encoding)
    const float* w1 = (const float*)d_in[2];
    const float* b1 = (const float*)d_in[3];
    const float* w2 = (const float*)d_in[4];
    const float* b2 = (const float*)d_in[5];
    const float* w3 = (const float*)d_in[6];
    const float* b3 = (const float*)d_in[7];

    float* ws   = (float*)d_ws;
    float* W1T  = ws + OFF_W1T;
    float* W2T  = ws + OFF_W2T;
    float* v    = ws + OFF_V;
    float* dlog = ws + OFF_D;
    int* isb = (int*)(ws + OFF_ISB);
    int* sid = (int*)(ws + OFF_SID);
    int* sst = (int*)(ws + OFF_SST);
    int* sen = (int*)(ws + OFF_SEN);
    int* nv  = (int*)(ws + OFF_NV);
    int* uct = (int*)(ws + OFF_UCT);
    int* ul  = (int*)(ws + OFF_UL);

    float* out = (float*)d_out;
    float* h1  = out;   // stage h1 (B*T*H floats) in the new_logits region; overwritten by pool at the end

    hipMemsetAsync(dlog, 0, BT * sizeof(float), stream);
    hipMemsetAsync(sst, 0xFF, BT * sizeof(int), stream);
    hipMemsetAsync(sen, 0xFF, BT * sizeof(int), stream);
    hipMemsetAsync(uct, 0, sizeof(int), stream);

    repack_kernel<<<1024, 256, 0, stream>>>(w1, w2, w3, W1T, W2T, v);
    conv1_kernel<<<dim3(BSZ * (T / 64), HDIM / 64), 256, 0, stream>>>(x, W1T, b1, h1);
    conv2_kernel<<<dim3(BSZ * (T / 64), HDIM / 64), 256, 0, stream>>>(h1, W2T, b2, v, dlog);
    boundary_kernel<<<BT / 256, 256, 0, stream>>>(dlog, padmask, b3, isb, uct, ul);
    recheck_kernel<<<1024, 256, 0, stream>>>(x, W1T, W2T, b1, b2, w3, b3, ul, uct, isb);
    scan_kernel<<<BSZ, 1024, 0, stream>>>(isb, padmask, sid, nv);
    segbounds_kernel<<<BT / 256, 256, 0, stream>>>(sid, padmask, sst, sen);
    pool_kernel<<<BT / 4, 256, 0, stream>>>(x, sst, sen, nv, out);
}

// Round 2
// 1232.300 us; speedup vs baseline: 3.5333x; 3.5333x over previous
//
#include <hip/hip_runtime.h>
#include <cstdint>
#include <cstddef>

#define BSZ 16
#define T   8192
#define CDIM 256
#define HDIM 256
#define KW  7

constexpr int BT = BSZ * T;                  // 131072
constexpr float TAU = 2e-3f;                 // f64 recheck band for |d|
constexpr int UCAP = 32768;

typedef __attribute__((ext_vector_type(8))) short short8;
typedef __attribute__((ext_vector_type(4))) float f32x4;

// ---------------- workspace layout (byte offsets, all 16B-aligned) ----------------
constexpr size_t B_W1T  = 0;                         // f32 [7][256][256]  1835008 B
constexpr size_t B_W2T  = B_W1T + 1835008;           // f32 [3][256][256]   786432 B
constexpr size_t B_V    = B_W2T + 786432;            // f32 [256]             1024 B
constexpr size_t B_D    = B_V + 1024;                // f32 [BT]            524288 B
constexpr size_t B_ISB  = B_D + 524288;              // i32 [BT]
constexpr size_t B_SID  = B_ISB + 524288;            // i32 [BT]
constexpr size_t B_SST  = B_SID + 524288;            // i32 [BT]
constexpr size_t B_SEN  = B_SST + 524288;            // i32 [BT]
constexpr size_t B_NV   = B_SEN + 524288;            // i32 [16]
constexpr size_t B_UCT  = B_NV + 64;                 // i32 [1]
constexpr size_t B_UL   = B_UCT + 16;                // i32 [UCAP]
constexpr size_t B_ZERO = B_UL + 131072;             // 256 B of zeros
constexpr size_t B_W1HI = B_ZERO + 256;              // u16 [256][1792]     917504 B
constexpr size_t B_W1LO = B_W1HI + 917504;
constexpr size_t B_W2HI = B_W1LO + 917504;           // u16 [256][768]      393216 B
constexpr size_t B_W2LO = B_W2HI + 393216;           // total ~8.0 MB

// async global->LDS, 16B per lane; LDS dest = wave-uniform base + lane*16
__device__ __forceinline__ void gl_lds16(const void* g, void* l) {
    __builtin_amdgcn_global_load_lds(
        (const __attribute__((address_space(1))) unsigned int*)g,
        (__attribute__((address_space(3))) unsigned int*)l,
        16, 0, 0);
}

// split 8 f32 into bf16 hi (trunc) + bf16 lo (trunc of residual)
__device__ __forceinline__ void split8(const float4 u, const float4 v,
                                       short8& hi, short8& lo) {
    float f[8] = {u.x, u.y, u.z, u.w, v.x, v.y, v.z, v.w};
    #pragma unroll
    for (int i = 0; i < 8; ++i) {
        unsigned int b = __float_as_uint(f[i]);
        hi[i] = (short)(b >> 16);
        float l = f[i] - __uint_as_float(b & 0xFFFF0000u);
        lo[i] = (short)(__float_as_uint(l) >> 16);
    }
}

// ---------------- weight repack ----------------
// W1T[k][c][h] (f32, for f64 recheck); W1hi/lo[h][kw*256+c] bf16 split; same for w2; v[h]=w3[1,h]-w3[0,h]
__global__ void repack_kernel(const float* __restrict__ w1, const float* __restrict__ w2,
                              const float* __restrict__ w3,
                              float* __restrict__ W1T, float* __restrict__ W2T,
                              float* __restrict__ v,
                              unsigned short* __restrict__ W1hi, unsigned short* __restrict__ W1lo,
                              unsigned short* __restrict__ W2hi, unsigned short* __restrict__ W2lo)
{
    int idx = blockIdx.x * blockDim.x + threadIdx.x;
    int stride = gridDim.x * blockDim.x;
    for (int i = idx; i < KW * CDIM * HDIM; i += stride) {
        int k = i / (CDIM * HDIM), c = (i / HDIM) % CDIM, h = i % HDIM;
        W1T[i] = w1[(size_t)h * (CDIM * KW) + c * KW + k];
    }
    for (int i = idx; i < 3 * HDIM * HDIM; i += stride) {
        int k = i / (HDIM * HDIM), c = (i / HDIM) % HDIM, h = i % HDIM;
        W2T[i] = w2[(size_t)h * (HDIM * 3) + c * 3 + k];
    }
    for (int i = idx; i < HDIM * 1792; i += stride) {
        int h = i / 1792, kc = i % 1792, kw = kc >> 8, c = kc & 255;
        float f = w1[(size_t)h * 1792 + c * 7 + kw];
        unsigned int b = __float_as_uint(f);
        W1hi[i] = (unsigned short)(b >> 16);
        float lo = f - __uint_as_float(b & 0xFFFF0000u);
        W1lo[i] = (unsigned short)(__float_as_uint(lo) >> 16);
    }
    for (int i = idx; i < HDIM * 768; i += stride) {
        int h = i / 768, kc = i % 768, kw = kc >> 8, c = kc & 255;
        float f = w2[(size_t)h * 768 + c * 3 + kw];
        unsigned int b = __float_as_uint(f);
        W2hi[i] = (unsigned short)(b >> 16);
        float lo = f - __uint_as_float(b & 0xFFFF0000u);
        W2lo[i] = (unsigned short)(__float_as_uint(lo) >> 16);
    }
    if (idx < HDIM) v[idx] = w3[HDIM + idx] - w3[idx];
}

// ---------------- conv1 via split-bf16 MFMA ----------------
// GEMM view: out[t,h] = sum_{kc} A[t,kc]*B[kc,h], kc=kw*256+c, A[t,kc]=x[t+kw-3,c]
// 128x128 block tile, 4 waves (2x2 of 64x64), BK=32, 56 K-chunks.
__global__ __launch_bounds__(256) void conv1_mfma(
    const float* __restrict__ x,
    const unsigned short* __restrict__ Whi, const unsigned short* __restrict__ Wlo,
    const float* __restrict__ b1, const float* __restrict__ zerobuf,
    float* __restrict__ h1)
{
    __shared__ float4 As4[1024];     // [k2 0..7][row 0..127]  16 KB (f32 A tile)
    __shared__ short8 Bh8[512];      // [q 0..3][row 0..127]    8 KB
    __shared__ short8 Bl8[512];      //                         8 KB
    const int tid = threadIdx.x;
    const int lane = tid & 63, wid = tid >> 6;
    const int b  = blockIdx.x >> 6;
    const int t0 = (blockIdx.x & 63) << 7;
    const int h0 = blockIdx.y << 7;
    const int wrow = wid >> 1, wcol = wid & 1;
    const int q = lane >> 4, l15 = lane & 15;
    const float* xb = x + (size_t)b * T * CDIM;

    f32x4 acc[4][4] = {};

    for (int ch = 0; ch < 56; ++ch) {
        const int kw = ch >> 3, c0 = (ch & 7) << 5;
        // stage A (f32): 16 wave-segments of 1KB; wave w does 4
        #pragma unroll
        for (int i2 = 0; i2 < 4; ++i2) {
            int s = wid * 4 + i2;
            int k2 = s >> 1, r = ((s & 1) << 6) + lane;
            int tA = t0 + r + kw - 3;
            const float* src = (tA >= 0 && tA < T)
                ? xb + (size_t)tA * CDIM + c0 + k2 * 4 : zerobuf;
            gl_lds16(src, (char*)As4 + (size_t)s * 1024);
        }
        // stage B hi/lo (bf16): 8 segments each; wave w does 2+2
        #pragma unroll
        for (int i2 = 0; i2 < 2; ++i2) {
            int s = wid * 2 + i2;
            int qq = s >> 1, r = ((s & 1) << 6) + lane;
            size_t off = (size_t)(h0 + r) * 1792 + ch * 32 + qq * 8;
            gl_lds16(Whi + off, (char*)Bh8 + (size_t)s * 1024);
            gl_lds16(Wlo + off, (char*)Bl8 + (size_t)s * 1024);
        }
        __syncthreads();

        short8 ah[4], al[4], bh[4], bl[4];
        #pragma unroll
        for (int i = 0; i < 4; ++i) {
            int m = wrow * 64 + i * 16 + l15;
            float4 u = As4[(2 * q) * 128 + m];
            float4 w = As4[(2 * q + 1) * 128 + m];
            split8(u, w, ah[i], al[i]);
        }
        #pragma unroll
        for (int j = 0; j < 4; ++j) {
            int n = wcol * 64 + j * 16 + l15;
            bh[j] = Bh8[q * 128 + n];
            bl[j] = Bl8[q * 128 + n];
        }
        #pragma unroll
        for (int i = 0; i < 4; ++i)
            #pragma unroll
            for (int j = 0; j < 4; ++j) {
                acc[i][j] = __builtin_amdgcn_mfma_f32_16x16x32_bf16(ah[i], bh[j], acc[i][j], 0, 0, 0);
                acc[i][j] = __builtin_amdgcn_mfma_f32_16x16x32_bf16(ah[i], bl[j], acc[i][j], 0, 0, 0);
                acc[i][j] = __builtin_amdgcn_mfma_f32_16x16x32_bf16(al[i], bh[j], acc[i][j], 0, 0, 0);
            }
        __syncthreads();
    }
    // epilogue: bias + relu, store h1 f32
    #pragma unroll
    for (int j = 0; j < 4; ++j) {
        int h = h0 + wcol * 64 + j * 16 + l15;
        float bb = b1[h];
        #pragma unroll
        for (int i = 0; i < 4; ++i) {
            int tb = t0 + wrow * 64 + i * 16 + q * 4;
            #pragma unroll
            for (int r = 0; r < 4; ++r)
                h1[(size_t)(b * T + tb + r) * HDIM + h] = fmaxf(acc[i][j][r] + bb, 0.f);
        }
    }
}

// ---------------- conv2 via split-bf16 MFMA, fused 1x1 score ----------------
__global__ __launch_bounds__(256) void conv2_mfma(
    const float* __restrict__ h1,
    const unsigned short* __restrict__ Whi, const unsigned short* __restrict__ Wlo,
    const float* __restrict__ b2, const float* __restrict__ v,
    const float* __restrict__ zerobuf, float* __restrict__ dlog)
{
    __shared__ float4 As4[1024];
    __shared__ short8 Bh8[512];
    __shared__ short8 Bl8[512];
    const int tid = threadIdx.x;
    const int lane = tid & 63, wid = tid >> 6;
    const int b  = blockIdx.x >> 6;
    const int t0 = (blockIdx.x & 63) << 7;
    const int h0 = blockIdx.y << 7;
    const int wrow = wid >> 1, wcol = wid & 1;
    const int q = lane >> 4, l15 = lane & 15;
    const float* hb = h1 + (size_t)b * T * HDIM;

    f32x4 acc[4][4] = {};

    for (int ch = 0; ch < 24; ++ch) {
        const int kw = ch >> 3, c0 = (ch & 7) << 5;
        #pragma unroll
        for (int i2 = 0; i2 < 4; ++i2) {
            int s = wid * 4 + i2;
            int k2 = s >> 1, r = ((s & 1) << 6) + lane;
            int tA = t0 + r + kw - 1;
            const float* src = (tA >= 0 && tA < T)
                ? hb + (size_t)tA * HDIM + c0 + k2 * 4 : zerobuf;
            gl_lds16(src, (char*)As4 + (size_t)s * 1024);
        }
        #pragma unroll
        for (int i2 = 0; i2 < 2; ++i2) {
            int s = wid * 2 + i2;
            int qq = s >> 1, r = ((s & 1) << 6) + lane;
            size_t off = (size_t)(h0 + r) * 768 + ch * 32 + qq * 8;
            gl_lds16(Whi + off, (char*)Bh8 + (size_t)s * 1024);
            gl_lds16(Wlo + off, (char*)Bl8 + (size_t)s * 1024);
        }
        __syncthreads();

        short8 ah[4], al[4], bh[4], bl[4];
        #pragma unroll
        for (int i = 0; i < 4; ++i) {
            int m = wrow * 64 + i * 16 + l15;
            float4 u = As4[(2 * q) * 128 + m];
            float4 w = As4[(2 * q + 1) * 128 + m];
            split8(u, w, ah[i], al[i]);
        }
        #pragma unroll
        for (int j = 0; j < 4; ++j) {
            int n = wcol * 64 + j * 16 + l15;
            bh[j] = Bh8[q * 128 + n];
            bl[j] = Bl8[q * 128 + n];
        }
        #pragma unroll
        for (int i = 0; i < 4; ++i)
            #pragma unroll
            for (int j = 0; j < 4; ++j) {
                acc[i][j] = __builtin_amdgcn_mfma_f32_16x16x32_bf16(ah[i], bh[j], acc[i][j], 0, 0, 0);
                acc[i][j] = __builtin_amdgcn_mfma_f32_16x16x32_bf16(ah[i], bl[j], acc[i][j], 0, 0, 0);
                acc[i][j] = __builtin_amdgcn_mfma_f32_16x16x32_bf16(al[i], bh[j], acc[i][j], 0, 0, 0);
            }
        __syncthreads();
    }
    // epilogue: p = sum_h v[h]*relu(h2+b2); reduce over the 16 lanes of each quad
    float vv[4], bb[4];
    #pragma unroll
    for (int j = 0; j < 4; ++j) {
        int h = h0 + wcol * 64 + j * 16 + l15;
        vv[j] = v[h]; bb[j] = b2[h];
    }
    #pragma unroll
    for (int i = 0; i < 4; ++i) {
        int tb = t0 + wrow * 64 + i * 16 + q * 4;
        #pragma unroll
        for (int r = 0; r < 4; ++r) {
            float s = 0.f;
            #pragma unroll
            for (int j = 0; j < 4; ++j)
                s += fmaxf(acc[i][j][r] + bb[j], 0.f) * vv[j];
            #pragma unroll
            for (int m = 1; m < 16; m <<= 1)
                s += __shfl_xor(s, m, 64);
            if (l15 == 0) atomicAdd(&dlog[b * T + tb + r], s);
        }
    }
}

// ---------------- boundary bit + uncertainty list ----------------
__global__ void boundary_kernel(const float* __restrict__ d, const int* __restrict__ padmask,
                                const float* __restrict__ b3,
                                int* __restrict__ isb, int* __restrict__ ucount,
                                int* __restrict__ ulist)
{
    int bt = blockIdx.x * 256 + threadIdx.x;
    if (bt >= BT) return;
    int pad = padmask[bt];
    float dd = d[bt] + (b3[1] - b3[0]);
    isb[bt] = (pad == 0 && dd > 0.f) ? 1 : 0;
    if (pad == 0 && fabsf(dd) < TAU) {
        int slot = atomicAdd(ucount, 1);
        if (slot < UCAP) ulist[slot] = bt;
    }
}

// ---------------- exact f64 recheck of near-tie tokens ----------------
__global__ __launch_bounds__(256) void recheck_kernel(
    const float* __restrict__ x, const float* __restrict__ W1T,
    const float* __restrict__ W2T, const float* __restrict__ b1,
    const float* __restrict__ b2, const float* __restrict__ w3,
    const float* __restrict__ b3,
    const int* __restrict__ ulist, const int* __restrict__ ucount,
    int* __restrict__ isb)
{
    __shared__ double h1s[3][HDIM];
    __shared__ double red[HDIM];
    int n = *ucount; if (n > UCAP) n = UCAP;
    const int h = threadIdx.x;
    for (int li = blockIdx.x; li < n; li += gridDim.x) {
        int bt = ulist[li];
        int b = bt >> 13, t = bt & (T - 1);
        #pragma unroll
        for (int dt = -1; dt <= 1; ++dt) {
            double acc = (double)b1[h];
            int tc = t + dt;
            if (tc >= 0 && tc < T) {
                for (int k = 0; k < KW; ++k) {
                    int tt = tc + k - 3;
                    if (tt < 0 || tt >= T) continue;
                    const float* xrow = &x[(size_t)(b * T + tt) * CDIM];
                    const float* wrow = &W1T[(size_t)k * 65536 + h];
                    for (int c = 0; c < CDIM; ++c)
                        acc += (double)xrow[c] * (double)wrow[(size_t)c * 256];
                }
            }
            h1s[dt + 1][h] = acc > 0.0 ? acc : 0.0;
        }
        __syncthreads();
        double acc2 = (double)b2[h];
        for (int k = 0; k < 3; ++k) {
            int tt = t + k - 1;
            if (tt < 0 || tt >= T) continue;
            const double* hrow = h1s[k];
            const float* wrow = &W2T[(size_t)k * 65536 + h];
            for (int c = 0; c < HDIM; ++c)
                acc2 += hrow[c] * (double)wrow[(size_t)c * 256];
        }
        double h2v = acc2 > 0.0 ? acc2 : 0.0;
        double vd = (double)w3[HDIM + h] - (double)w3[h];
        red[h] = vd * h2v;
        __syncthreads();
        for (int off = 128; off > 0; off >>= 1) {
            if (h < off) red[h] += red[h + off];
            __syncthreads();
        }
        if (h == 0) {
            double dd = red[0] + ((double)b3[1] - (double)b3[0]);
            isb[bt] = (dd > 0.0) ? 1 : 0;
        }
        __syncthreads();
    }
}

// ---------------- per-batch inclusive cumsum -> seg_id, n_valid ----------------
__global__ __launch_bounds__(1024) void scan_kernel(
    const int* __restrict__ isb, const int* __restrict__ padmask,
    int* __restrict__ sid, int* __restrict__ nvalid)
{
    __shared__ int ssum[1024];
    const int b = blockIdx.x, tid = threadIdx.x;
    const int base = b * T;
    int vals[8]; int s = 0;
    #pragma unroll
    for (int i = 0; i < 8; ++i) { vals[i] = isb[base + tid * 8 + i]; s += vals[i]; }
    ssum[tid] = s;
    __syncthreads();
    for (int off = 1; off < 1024; off <<= 1) {
        int add = (tid >= off) ? ssum[tid - off] : 0;
        __syncthreads();
        ssum[tid] += add;
        __syncthreads();
    }
    int run = ssum[tid] - s;
    #pragma unroll
    for (int i = 0; i < 8; ++i) {
        int t = tid * 8 + i;
        run += vals[i];
        sid[base + t] = (padmask[base + t] != 0) ? T : run;
    }
    if (tid == 1023) {
        int nb = ssum[1023];
        nvalid[b] = (padmask[base] == 0) ? (nb + 1) : 0;
    }
}

// ---------------- segment range extraction ----------------
__global__ void segbounds_kernel(const int* __restrict__ sid, const int* __restrict__ padmask,
                                 int* __restrict__ sst, int* __restrict__ sen)
{
    int bt = blockIdx.x * 256 + threadIdx.x;
    if (bt >= BT) return;
    if (padmask[bt] != 0) return;
    int t = bt & (T - 1);
    int b = bt >> 13;
    int s = sid[bt];
    if (t == 0) {
        if (s < T) sst[b * T + s] = 0;
    } else if (s != sid[bt - 1]) {
        if (s < T) sst[b * T + s] = t;
    }
    bool last = (t == T - 1) || (padmask[bt + 1] != 0);
    if (s < T && (last || sid[bt + 1] != s)) sen[b * T + s] = t + 1;
}

// ---------------- segment-mean pooling + new_pad ----------------
__global__ __launch_bounds__(256) void pool_kernel(
    const float* __restrict__ x, const int* __restrict__ sst,
    const int* __restrict__ sen, const int* __restrict__ nvalid,
    float* __restrict__ out)
{
    int slot = blockIdx.x * 4 + (threadIdx.x >> 6);
    int lane = threadIdx.x & 63;
    int b = slot >> 13;
    int s = slot & (T - 1);
    int nv = nvalid[b];
    float4 res = make_float4(0.f, 0.f, 0.f, 0.f);
    if (s < nv) {
        int st = sst[slot], en = sen[slot];
        if (st >= 0 && en > st) {
            float4 a = make_float4(0.f, 0.f, 0.f, 0.f);
            const float* xp = &x[(size_t)(b * T + st) * CDIM + lane * 4];
            for (int t = st; t < en; ++t) {
                float4 xv = *(const float4*)xp;
                a.x += xv.x; a.y += xv.y; a.z += xv.z; a.w += xv.w;
                xp += CDIM;
            }
            float inv = 1.f / (float)(en - st);
            res = make_float4(a.x * inv, a.y * inv, a.z * inv, a.w * inv);
        }
    }
    *(float4*)&out[(size_t)slot * CDIM + lane * 4] = res;
    if (lane == 0) out[(size_t)BT * CDIM + slot] = (s < nv) ? 0.f : 1.f;
}

extern "C" void kernel_launch(void* const* d_in, const int* in_sizes, int n_in,
                              void* d_out, int out_size, void* d_ws, size_t ws_size,
                              hipStream_t stream)
{
    const float* x  = (const float*)d_in[0];
    const int* padmask = (const int*)d_in[1];
    const float* w1 = (const float*)d_in[2];
    const float* b1 = (const float*)d_in[3];
    const float* w2 = (const float*)d_in[4];
    const float* b2 = (const float*)d_in[5];
    const float* w3 = (const float*)d_in[6];
    const float* b3 = (const float*)d_in[7];

    char* ws = (char*)d_ws;
    float* W1T = (float*)(ws + B_W1T);
    float* W2T = (float*)(ws + B_W2T);
    float* v   = (float*)(ws + B_V);
    float* dlog = (float*)(ws + B_D);
    int* isb = (int*)(ws + B_ISB);
    int* sid = (int*)(ws + B_SID);
    int* sst = (int*)(ws + B_SST);
    int* sen = (int*)(ws + B_SEN);
    int* nv  = (int*)(ws + B_NV);
    int* uct = (int*)(ws + B_UCT);
    int* ul  = (int*)(ws + B_UL);
    float* zerobuf = (float*)(ws + B_ZERO);
    unsigned short* W1hi = (unsigned short*)(ws + B_W1HI);
    unsigned short* W1lo = (unsigned short*)(ws + B_W1LO);
    unsigned short* W2hi = (unsigned short*)(ws + B_W2HI);
    unsigned short* W2lo = (unsigned short*)(ws + B_W2LO);

    float* out = (float*)d_out;
    float* h1  = out;   // h1 (BT x 256 f32) staged in the new_logits region; pool overwrites last

    hipMemsetAsync(dlog, 0, BT * sizeof(float), stream);
    hipMemsetAsync(sst, 0xFF, BT * sizeof(int), stream);
    hipMemsetAsync(sen, 0xFF, BT * sizeof(int), stream);
    hipMemsetAsync(uct, 0, sizeof(int), stream);
    hipMemsetAsync(zerobuf, 0, 256, stream);

    repack_kernel<<<1024, 256, 0, stream>>>(w1, w2, w3, W1T, W2T, v,
                                            W1hi, W1lo, W2hi, W2lo);
    conv1_mfma<<<dim3(BSZ * (T / 128), HDIM / 128), 256, 0, stream>>>(
        x, W1hi, W1lo, b1, zerobuf, h1);
    conv2_mfma<<<dim3(BSZ * (T / 128), HDIM / 128), 256, 0, stream>>>(
        h1, W2hi, W2lo, b2, v, zerobuf, dlog);
    boundary_kernel<<<BT / 256, 256, 0, stream>>>(dlog, padmask, b3, isb, uct, ul);
    recheck_kernel<<<1024, 256, 0, stream>>>(x, W1T, W2T, b1, b2, w3, b3, ul, uct, isb);
    scan_kernel<<<BSZ, 1024, 0, stream>>>(isb, padmask, sid, nv);
    segbounds_kernel<<<BT / 256, 256, 0, stream>>>(sid, padmask, sst, sen);
    pool_kernel<<<BT / 4, 256, 0, stream>>>(x, sst, sen, nv, out);
}

// Round 3
// 1078.917 us; speedup vs baseline: 4.0357x; 1.1422x over previous
//
#include <hip/hip_runtime.h>
#include <cstdint>
#include <cstddef>

#define BSZ 16
#define T   8192
#define CDIM 256
#define HDIM 256
#define KW  7

constexpr int BT = BSZ * T;                  // 131072
constexpr float TAU = 2e-3f;                 // f64 recheck band for |d|
constexpr int UCAP = 32768;

typedef __attribute__((ext_vector_type(8))) short short8;
typedef __attribute__((ext_vector_type(4))) float f32x4;

// ---------------- workspace layout (byte offsets, all 16B-aligned) ----------------
constexpr size_t B_W1T  = 0;                         // f32 [7][256][256]  1835008 B
constexpr size_t B_W2T  = B_W1T + 1835008;           // f32 [3][256][256]   786432 B
constexpr size_t B_V    = B_W2T + 786432;            // f32 [256]             1024 B
constexpr size_t B_D    = B_V + 1024;                // f32 [BT]            524288 B
constexpr size_t B_ISB  = B_D + 524288;              // i32 [BT]
constexpr size_t B_SID  = B_ISB + 524288;            // i32 [BT]
constexpr size_t B_SST  = B_SID + 524288;            // i32 [BT]
constexpr size_t B_SEN  = B_SST + 524288;            // i32 [BT]
constexpr size_t B_NV   = B_SEN + 524288;            // i32 [16]
constexpr size_t B_UCT  = B_NV + 64;                 // i32 [1]
constexpr size_t B_UL   = B_UCT + 16;                // i32 [UCAP]
constexpr size_t B_W1HI = B_UL + 131072;             // u16 [256][1792]     917504 B
constexpr size_t B_W1LO = B_W1HI + 917504;
constexpr size_t B_W2HI = B_W1LO + 917504;           // u16 [256][768]      393216 B
constexpr size_t B_W2LO = B_W2HI + 393216;           // total ~8.0 MB

// async global->LDS, 16B per lane; LDS dest = wave-uniform base + lane*16
__device__ __forceinline__ void gl_lds16(const void* g, void* l) {
    __builtin_amdgcn_global_load_lds(
        (const __attribute__((address_space(1))) unsigned int*)g,
        (__attribute__((address_space(3))) unsigned int*)l,
        16, 0, 0);
}

// split 8 f32 into bf16 hi (trunc) + bf16 lo (trunc of residual)
__device__ __forceinline__ void split8(const float4 u, const float4 v,
                                       short8& hi, short8& lo) {
    float f[8] = {u.x, u.y, u.z, u.w, v.x, v.y, v.z, v.w};
    #pragma unroll
    for (int i = 0; i < 8; ++i) {
        unsigned int b = __float_as_uint(f[i]);
        hi[i] = (short)(b >> 16);
        float l = f[i] - __uint_as_float(b & 0xFFFF0000u);
        lo[i] = (short)(__float_as_uint(l) >> 16);
    }
}

// ---------------- weight repack ----------------
__global__ void repack_kernel(const float* __restrict__ w1, const float* __restrict__ w2,
                              const float* __restrict__ w3,
                              float* __restrict__ W1T, float* __restrict__ W2T,
                              float* __restrict__ v,
                              unsigned short* __restrict__ W1hi, unsigned short* __restrict__ W1lo,
                              unsigned short* __restrict__ W2hi, unsigned short* __restrict__ W2lo)
{
    int idx = blockIdx.x * blockDim.x + threadIdx.x;
    int stride = gridDim.x * blockDim.x;
    for (int i = idx; i < KW * CDIM * HDIM; i += stride) {
        int k = i / (CDIM * HDIM), c = (i / HDIM) % CDIM, h = i % HDIM;
        W1T[i] = w1[(size_t)h * (CDIM * KW) + c * KW + k];
    }
    for (int i = idx; i < 3 * HDIM * HDIM; i += stride) {
        int k = i / (HDIM * HDIM), c = (i / HDIM) % HDIM, h = i % HDIM;
        W2T[i] = w2[(size_t)h * (HDIM * 3) + c * 3 + k];
    }
    for (int i = idx; i < HDIM * 1792; i += stride) {
        int h = i / 1792, kc = i % 1792, kw = kc >> 8, c = kc & 255;
        float f = w1[(size_t)h * 1792 + c * 7 + kw];
        unsigned int b = __float_as_uint(f);
        W1hi[i] = (unsigned short)(b >> 16);
        float lo = f - __uint_as_float(b & 0xFFFF0000u);
        W1lo[i] = (unsigned short)(__float_as_uint(lo) >> 16);
    }
    for (int i = idx; i < HDIM * 768; i += stride) {
        int h = i / 768, kc = i % 768, kw = kc >> 8, c = kc & 255;
        float f = w2[(size_t)h * 768 + c * 3 + kw];
        unsigned int b = __float_as_uint(f);
        W2hi[i] = (unsigned short)(b >> 16);
        float lo = f - __uint_as_float(b & 0xFFFF0000u);
        W2lo[i] = (unsigned short)(__float_as_uint(lo) >> 16);
    }
    if (idx < HDIM) v[idx] = w3[HDIM + idx] - w3[idx];
}

// ---------------- conv1: c-chunk outer, kw inner, pre-split A window in LDS ----------------
// 128 t x 128 h block, 4 waves 2x2. A window: 136 rows x 32 c (bf16 hi/lo).
// B double-buffered via global_load_lds; one barrier per kw-iter.
__global__ __launch_bounds__(256) void conv1_mfma(
    const float* __restrict__ x,
    const unsigned short* __restrict__ Whi, const unsigned short* __restrict__ Wlo,
    const float* __restrict__ b1,
    unsigned short* __restrict__ h1hi, unsigned short* __restrict__ h1lo)
{
    __shared__ short8 Ah8[544];      // [q 0..3][row 0..135]
    __shared__ short8 Al8[544];
    __shared__ short8 Bh8[1024];     // 2 buffers x [q 0..3][n 0..127]
    __shared__ short8 Bl8[1024];
    const int tid = threadIdx.x;
    const int lane = tid & 63, wid = tid >> 6;
    const int b  = blockIdx.x >> 6;
    const int t0 = (blockIdx.x & 63) << 7;
    const int h0 = blockIdx.y << 7;
    const int wrow = wid >> 1, wcol = wid & 1;
    const int q = lane >> 4, l15 = lane & 15;
    const float* xb = x + (size_t)b * T * CDIM;

    f32x4 acc[4][4] = {};

    for (int cc = 0; cc < 8; ++cc) {
        const int c0 = cc << 5;
        // stage A window: 136 rows x 32 c, split to bf16 hi/lo
        for (int s = tid; s < 544; s += 256) {
            int qq = s / 136, r = s - qq * 136;
            int t = t0 + r - 3;
            float4 u = {}, w = {};
            if (t >= 0 && t < T) {
                const float* src = xb + (size_t)t * CDIM + c0 + qq * 8;
                u = *(const float4*)src;
                w = *(const float4*)(src + 4);
            }
            short8 hi, lo;
            split8(u, w, hi, lo);
            Ah8[qq * 136 + r] = hi;
            Al8[qq * 136 + r] = lo;
        }
        // stage B(kw=0) into buffer 0
        #pragma unroll
        for (int i2 = 0; i2 < 2; ++i2) {
            int s = wid * 2 + i2;
            int qq = s >> 1, r = ((s & 1) << 6) + lane;
            size_t off = (size_t)(h0 + r) * 1792 + c0 + qq * 8;
            gl_lds16(Whi + off, (char*)&Bh8[0] + (size_t)s * 1024);
            gl_lds16(Wlo + off, (char*)&Bl8[0] + (size_t)s * 1024);
        }
        __syncthreads();

        for (int kw = 0; kw < KW; ++kw) {
            // prefetch next kw's B tile into the other buffer
            if (kw < KW - 1) {
                int nbuf = (kw + 1) & 1;
                #pragma unroll
                for (int i2 = 0; i2 < 2; ++i2) {
                    int s = wid * 2 + i2;
                    int qq = s >> 1, r = ((s & 1) << 6) + lane;
                    size_t off = (size_t)(h0 + r) * 1792 + (size_t)(kw + 1) * 256 + c0 + qq * 8;
                    gl_lds16(Whi + off, (char*)&Bh8[nbuf * 512] + (size_t)s * 1024);
                    gl_lds16(Wlo + off, (char*)&Bl8[nbuf * 512] + (size_t)s * 1024);
                }
            }
            const int cur = (kw & 1) * 512;
            short8 ah[4], al[4], bh[4], bl[4];
            const int rbase = wrow * 64 + l15 + kw;
            #pragma unroll
            for (int i = 0; i < 4; ++i) {
                ah[i] = Ah8[q * 136 + rbase + i * 16];
                al[i] = Al8[q * 136 + rbase + i * 16];
            }
            #pragma unroll
            for (int j = 0; j < 4; ++j) {
                int n = wcol * 64 + j * 16 + l15;
                bh[j] = Bh8[cur + q * 128 + n];
                bl[j] = Bl8[cur + q * 128 + n];
            }
            #pragma unroll
            for (int i = 0; i < 4; ++i)
                #pragma unroll
                for (int j = 0; j < 4; ++j) {
                    acc[i][j] = __builtin_amdgcn_mfma_f32_16x16x32_bf16(ah[i], bh[j], acc[i][j], 0, 0, 0);
                    acc[i][j] = __builtin_amdgcn_mfma_f32_16x16x32_bf16(ah[i], bl[j], acc[i][j], 0, 0, 0);
                    acc[i][j] = __builtin_amdgcn_mfma_f32_16x16x32_bf16(al[i], bh[j], acc[i][j], 0, 0, 0);
                }
            __syncthreads();
        }
    }
    // epilogue: bias + relu, write h1 as bf16 hi/lo pair
    #pragma unroll
    for (int j = 0; j < 4; ++j) {
        int h = h0 + wcol * 64 + j * 16 + l15;
        float bb = b1[h];
        #pragma unroll
        for (int i = 0; i < 4; ++i) {
            int tb = t0 + wrow * 64 + i * 16 + q * 4;
            #pragma unroll
            for (int r = 0; r < 4; ++r) {
                float val = fmaxf(acc[i][j][r] + bb, 0.f);
                unsigned int ub = __float_as_uint(val);
                float l = val - __uint_as_float(ub & 0xFFFF0000u);
                size_t idx = (size_t)(b * T + tb + r) * HDIM + h;
                h1hi[idx] = (unsigned short)(ub >> 16);
                h1lo[idx] = (unsigned short)(__float_as_uint(l) >> 16);
            }
        }
    }
}

// ---------------- conv2: same structure, A window copied from pre-split h1 ----------------
__global__ __launch_bounds__(256) void conv2_mfma(
    const unsigned short* __restrict__ h1hi, const unsigned short* __restrict__ h1lo,
    const unsigned short* __restrict__ Whi, const unsigned short* __restrict__ Wlo,
    const float* __restrict__ b2, const float* __restrict__ v,
    float* __restrict__ dlog)
{
    __shared__ short8 Ah8[528];      // [q 0..3][row 0..131]
    __shared__ short8 Al8[528];
    __shared__ short8 Bh8[1024];
    __shared__ short8 Bl8[1024];
    const int tid = threadIdx.x;
    const int lane = tid & 63, wid = tid >> 6;
    const int b  = blockIdx.x >> 6;
    const int t0 = (blockIdx.x & 63) << 7;
    const int h0 = blockIdx.y << 7;
    const int wrow = wid >> 1, wcol = wid & 1;
    const int q = lane >> 4, l15 = lane & 15;
    const short8* hbh = (const short8*)h1hi;
    const short8* hbl = (const short8*)h1lo;

    f32x4 acc[4][4] = {};

    for (int cc = 0; cc < 8; ++cc) {
        const int c0 = cc << 5;
        // stage A window: 132 rows x 32 c, direct bf16 copy (no split)
        for (int s = tid; s < 528; s += 256) {
            int qq = s / 132, r = s - qq * 132;
            int t = t0 + r - 1;
            short8 hi = {}, lo = {};
            if (t >= 0 && t < T) {
                size_t v8 = ((size_t)(b * T + t) * HDIM + c0 + qq * 8) >> 3;
                hi = hbh[v8];
                lo = hbl[v8];
            }
            Ah8[qq * 132 + r] = hi;
            Al8[qq * 132 + r] = lo;
        }
        #pragma unroll
        for (int i2 = 0; i2 < 2; ++i2) {
            int s = wid * 2 + i2;
            int qq = s >> 1, r = ((s & 1) << 6) + lane;
            size_t off = (size_t)(h0 + r) * 768 + c0 + qq * 8;
            gl_lds16(Whi + off, (char*)&Bh8[0] + (size_t)s * 1024);
            gl_lds16(Wlo + off, (char*)&Bl8[0] + (size_t)s * 1024);
        }
        __syncthreads();

        for (int kw = 0; kw < 3; ++kw) {
            if (kw < 2) {
                int nbuf = (kw + 1) & 1;
                #pragma unroll
                for (int i2 = 0; i2 < 2; ++i2) {
                    int s = wid * 2 + i2;
                    int qq = s >> 1, r = ((s & 1) << 6) + lane;
                    size_t off = (size_t)(h0 + r) * 768 + (size_t)(kw + 1) * 256 + c0 + qq * 8;
                    gl_lds16(Whi + off, (char*)&Bh8[nbuf * 512] + (size_t)s * 1024);
                    gl_lds16(Wlo + off, (char*)&Bl8[nbuf * 512] + (size_t)s * 1024);
                }
            }
            const int cur = (kw & 1) * 512;
            short8 ah[4], al[4], bh[4], bl[4];
            const int rbase = wrow * 64 + l15 + kw;
            #pragma unroll
            for (int i = 0; i < 4; ++i) {
                ah[i] = Ah8[q * 132 + rbase + i * 16];
                al[i] = Al8[q * 132 + rbase + i * 16];
            }
            #pragma unroll
            for (int j = 0; j < 4; ++j) {
                int n = wcol * 64 + j * 16 + l15;
                bh[j] = Bh8[cur + q * 128 + n];
                bl[j] = Bl8[cur + q * 128 + n];
            }
            #pragma unroll
            for (int i = 0; i < 4; ++i)
                #pragma unroll
                for (int j = 0; j < 4; ++j) {
                    acc[i][j] = __builtin_amdgcn_mfma_f32_16x16x32_bf16(ah[i], bh[j], acc[i][j], 0, 0, 0);
                    acc[i][j] = __builtin_amdgcn_mfma_f32_16x16x32_bf16(ah[i], bl[j], acc[i][j], 0, 0, 0);
                    acc[i][j] = __builtin_amdgcn_mfma_f32_16x16x32_bf16(al[i], bh[j], acc[i][j], 0, 0, 0);
                }
            __syncthreads();
        }
    }
    // epilogue: p = sum_h v[h]*relu(h2+b2); reduce over quad lanes
    float vv[4], bb[4];
    #pragma unroll
    for (int j = 0; j < 4; ++j) {
        int h = h0 + wcol * 64 + j * 16 + l15;
        vv[j] = v[h]; bb[j] = b2[h];
    }
    #pragma unroll
    for (int i = 0; i < 4; ++i) {
        int tb = t0 + wrow * 64 + i * 16 + q * 4;
        #pragma unroll
        for (int r = 0; r < 4; ++r) {
            float s = 0.f;
            #pragma unroll
            for (int j = 0; j < 4; ++j)
                s += fmaxf(acc[i][j][r] + bb[j], 0.f) * vv[j];
            #pragma unroll
            for (int m = 1; m < 16; m <<= 1)
                s += __shfl_xor(s, m, 64);
            if (l15 == 0) atomicAdd(&dlog[b * T + tb + r], s);
        }
    }
}

// ---------------- boundary bit + uncertainty list ----------------
__global__ void boundary_kernel(const float* __restrict__ d, const int* __restrict__ padmask,
                                const float* __restrict__ b3,
                                int* __restrict__ isb, int* __restrict__ ucount,
                                int* __restrict__ ulist)
{
    int bt = blockIdx.x * 256 + threadIdx.x;
    if (bt >= BT) return;
    int pad = padmask[bt];
    float dd = d[bt] + (b3[1] - b3[0]);
    isb[bt] = (pad == 0 && dd > 0.f) ? 1 : 0;
    if (pad == 0 && fabsf(dd) < TAU) {
        int slot = atomicAdd(ucount, 1);
        if (slot < UCAP) ulist[slot] = bt;
    }
}

// ---------------- exact f64 recheck of near-tie tokens ----------------
__global__ __launch_bounds__(256) void recheck_kernel(
    const float* __restrict__ x, const float* __restrict__ W1T,
    const float* __restrict__ W2T, const float* __restrict__ b1,
    const float* __restrict__ b2, const float* __restrict__ w3,
    const float* __restrict__ b3,
    const int* __restrict__ ulist, const int* __restrict__ ucount,
    int* __restrict__ isb)
{
    __shared__ double h1s[3][HDIM];
    __shared__ double red[HDIM];
    int n = *ucount; if (n > UCAP) n = UCAP;
    const int h = threadIdx.x;
    for (int li = blockIdx.x; li < n; li += gridDim.x) {
        int bt = ulist[li];
        int b = bt >> 13, t = bt & (T - 1);
        #pragma unroll
        for (int dt = -1; dt <= 1; ++dt) {
            double acc = (double)b1[h];
            int tc = t + dt;
            if (tc >= 0 && tc < T) {
                for (int k = 0; k < KW; ++k) {
                    int tt = tc + k - 3;
                    if (tt < 0 || tt >= T) continue;
                    const float* xrow = &x[(size_t)(b * T + tt) * CDIM];
                    const float* wrow = &W1T[(size_t)k * 65536 + h];
                    for (int c = 0; c < CDIM; ++c)
                        acc += (double)xrow[c] * (double)wrow[(size_t)c * 256];
                }
            }
            h1s[dt + 1][h] = acc > 0.0 ? acc : 0.0;
        }
        __syncthreads();
        double acc2 = (double)b2[h];
        for (int k = 0; k < 3; ++k) {
            int tt = t + k - 1;
            if (tt < 0 || tt >= T) continue;
            const double* hrow = h1s[k];
            const float* wrow = &W2T[(size_t)k * 65536 + h];
            for (int c = 0; c < HDIM; ++c)
                acc2 += hrow[c] * (double)wrow[(size_t)c * 256];
        }
        double h2v = acc2 > 0.0 ? acc2 : 0.0;
        double vd = (double)w3[HDIM + h] - (double)w3[h];
        red[h] = vd * h2v;
        __syncthreads();
        for (int off = 128; off > 0; off >>= 1) {
            if (h < off) red[h] += red[h + off];
            __syncthreads();
        }
        if (h == 0) {
            double dd = red[0] + ((double)b3[1] - (double)b3[0]);
            isb[bt] = (dd > 0.0) ? 1 : 0;
        }
        __syncthreads();
    }
}

// ---------------- per-batch inclusive cumsum -> seg_id, n_valid ----------------
__global__ __launch_bounds__(1024) void scan_kernel(
    const int* __restrict__ isb, const int* __restrict__ padmask,
    int* __restrict__ sid, int* __restrict__ nvalid)
{
    __shared__ int ssum[1024];
    const int b = blockIdx.x, tid = threadIdx.x;
    const int base = b * T;
    int vals[8]; int s = 0;
    #pragma unroll
    for (int i = 0; i < 8; ++i) { vals[i] = isb[base + tid * 8 + i]; s += vals[i]; }
    ssum[tid] = s;
    __syncthreads();
    for (int off = 1; off < 1024; off <<= 1) {
        int add = (tid >= off) ? ssum[tid - off] : 0;
        __syncthreads();
        ssum[tid] += add;
        __syncthreads();
    }
    int run = ssum[tid] - s;
    #pragma unroll
    for (int i = 0; i < 8; ++i) {
        int t = tid * 8 + i;
        run += vals[i];
        sid[base + t] = (padmask[base + t] != 0) ? T : run;
    }
    if (tid == 1023) {
        int nb = ssum[1023];
        nvalid[b] = (padmask[base] == 0) ? (nb + 1) : 0;
    }
}

// ---------------- segment range extraction ----------------
__global__ void segbounds_kernel(const int* __restrict__ sid, const int* __restrict__ padmask,
                                 int* __restrict__ sst, int* __restrict__ sen)
{
    int bt = blockIdx.x * 256 + threadIdx.x;
    if (bt >= BT) return;
    if (padmask[bt] != 0) return;
    int t = bt & (T - 1);
    int b = bt >> 13;
    int s = sid[bt];
    if (t == 0) {
        if (s < T) sst[b * T + s] = 0;
    } else if (s != sid[bt - 1]) {
        if (s < T) sst[b * T + s] = t;
    }
    bool last = (t == T - 1) || (padmask[bt + 1] != 0);
    if (s < T && (last || sid[bt + 1] != s)) sen[b * T + s] = t + 1;
}

// ---------------- segment-mean pooling + new_pad ----------------
__global__ __launch_bounds__(256) void pool_kernel(
    const float* __restrict__ x, const int* __restrict__ sst,
    const int* __restrict__ sen, const int* __restrict__ nvalid,
    float* __restrict__ out)
{
    int slot = blockIdx.x * 4 + (threadIdx.x >> 6);
    int lane = threadIdx.x & 63;
    int b = slot >> 13;
    int s = slot & (T - 1);
    int nv = nvalid[b];
    float4 res = make_float4(0.f, 0.f, 0.f, 0.f);
    if (s < nv) {
        int st = sst[slot], en = sen[slot];
        if (st >= 0 && en > st) {
            float4 a = make_float4(0.f, 0.f, 0.f, 0.f);
            const float* xp = &x[(size_t)(b * T + st) * CDIM + lane * 4];
            for (int t = st; t < en; ++t) {
                float4 xv = *(const float4*)xp;
                a.x += xv.x; a.y += xv.y; a.z += xv.z; a.w += xv.w;
                xp += CDIM;
            }
            float inv = 1.f / (float)(en - st);
            res = make_float4(a.x * inv, a.y * inv, a.z * inv, a.w * inv);
        }
    }
    *(float4*)&out[(size_t)slot * CDIM + lane * 4] = res;
    if (lane == 0) out[(size_t)BT * CDIM + slot] = (s < nv) ? 0.f : 1.f;
}

extern "C" void kernel_launch(void* const* d_in, const int* in_sizes, int n_in,
                              void* d_out, int out_size, void* d_ws, size_t ws_size,
                              hipStream_t stream)
{
    const float* x  = (const float*)d_in[0];
    const int* padmask = (const int*)d_in[1];
    const float* w1 = (const float*)d_in[2];
    const float* b1 = (const float*)d_in[3];
    const float* w2 = (const float*)d_in[4];
    const float* b2 = (const float*)d_in[5];
    const float* w3 = (const float*)d_in[6];
    const float* b3 = (const float*)d_in[7];

    char* ws = (char*)d_ws;
    float* W1T = (float*)(ws + B_W1T);
    float* W2T = (float*)(ws + B_W2T);
    float* v   = (float*)(ws + B_V);
    float* dlog = (float*)(ws + B_D);
    int* isb = (int*)(ws + B_ISB);
    int* sid = (int*)(ws + B_SID);
    int* sst = (int*)(ws + B_SST);
    int* sen = (int*)(ws + B_SEN);
    int* nv  = (int*)(ws + B_NV);
    int* uct = (int*)(ws + B_UCT);
    int* ul  = (int*)(ws + B_UL);
    unsigned short* W1hi = (unsigned short*)(ws + B_W1HI);
    unsigned short* W1lo = (unsigned short*)(ws + B_W1LO);
    unsigned short* W2hi = (unsigned short*)(ws + B_W2HI);
    unsigned short* W2lo = (unsigned short*)(ws + B_W2LO);

    float* out = (float*)d_out;
    // h1 staged as bf16 hi/lo pair inside the new_logits f32 region (same byte count)
    unsigned short* h1hi = (unsigned short*)out;
    unsigned short* h1lo = h1hi + (size_t)BT * HDIM;

    hipMemsetAsync(dlog, 0, BT * sizeof(float), stream);
    hipMemsetAsync(sst, 0xFF, BT * sizeof(int), stream);
    hipMemsetAsync(sen, 0xFF, BT * sizeof(int), stream);
    hipMemsetAsync(uct, 0, sizeof(int), stream);

    repack_kernel<<<1024, 256, 0, stream>>>(w1, w2, w3, W1T, W2T, v,
                                            W1hi, W1lo, W2hi, W2lo);
    conv1_mfma<<<dim3(BSZ * (T / 128), HDIM / 128), 256, 0, stream>>>(
        x, W1hi, W1lo, b1, h1hi, h1lo);
    conv2_mfma<<<dim3(BSZ * (T / 128), HDIM / 128), 256, 0, stream>>>(
        h1hi, h1lo, W2hi, W2lo, b2, v, dlog);
    boundary_kernel<<<BT / 256, 256, 0, stream>>>(dlog, padmask, b3, isb, uct, ul);
    recheck_kernel<<<1024, 256, 0, stream>>>(x, W1T, W2T, b1, b2, w3, b3, ul, uct, isb);
    scan_kernel<<<BSZ, 1024, 0, stream>>>(isb, padmask, sid, nv);
    segbounds_kernel<<<BT / 256, 256, 0, stream>>>(sid, padmask, sst, sen);
    pool_kernel<<<BT / 4, 256, 0, stream>>>(x, sst, sen, nv, out);
}

// Round 4
// 969.578 us; speedup vs baseline: 4.4908x; 1.1128x over previous
//
#include <hip/hip_runtime.h>
#include <cstdint>
#include <cstddef>

#define BSZ 16
#define T   8192
#define CDIM 256
#define HDIM 256
#define KW  7

constexpr int BT = BSZ * T;                  // 131072
constexpr float TAU = 1e-2f;                 // f64 recheck band for |d| (pure-bf16 path: sigma_d ~1.2e-3)
constexpr int UCAP = 32768;

typedef __attribute__((ext_vector_type(8))) short short8;
typedef __attribute__((ext_vector_type(4))) float f32x4;

// ---------------- workspace layout (byte offsets, all 16B-aligned) ----------------
constexpr size_t B_W1T  = 0;                         // f32 [7][256][256]  1835008 B (exact copy, for f64 recheck)
constexpr size_t B_W2T  = B_W1T + 1835008;           // f32 [3][256][256]   786432 B
constexpr size_t B_V    = B_W2T + 786432;            // f32 [256]
constexpr size_t B_D    = B_V + 1024;                // f32 [BT]
constexpr size_t B_ISB  = B_D + 524288;              // i32 [BT]
constexpr size_t B_SID  = B_ISB + 524288;            // i32 [BT]
constexpr size_t B_SST  = B_SID + 524288;            // i32 [BT]
constexpr size_t B_SEN  = B_SST + 524288;            // i32 [BT]
constexpr size_t B_NV   = B_SEN + 524288;            // i32 [16]
constexpr size_t B_UCT  = B_NV + 64;                 // i32 [1]
constexpr size_t B_UL   = B_UCT + 16;                // i32 [UCAP]
constexpr size_t B_ZERO = B_UL + 131072;             // 256 B of zeros (DMA clamp target)
constexpr size_t B_W1B  = B_ZERO + 256;              // bf16 [256][1792]    917504 B
constexpr size_t B_W2B  = B_W1B + 917504;            // bf16 [256][768]     393216 B  -> ~6.0 MB total

// async global->LDS, 16B per lane; LDS dest = wave-uniform base + lane*16 (global addr per-lane)
__device__ __forceinline__ void gl_lds16(const void* g, void* l) {
    __builtin_amdgcn_global_load_lds(
        (const __attribute__((address_space(1))) unsigned int*)g,
        (__attribute__((address_space(3))) unsigned int*)l,
        16, 0, 0);
}

__device__ __forceinline__ unsigned short bf16_rne(float f) {
    unsigned int u = __float_as_uint(f);
    u += 0x7FFFu + ((u >> 16) & 1u);
    return (unsigned short)(u >> 16);
}

// ---------------- weight repack ----------------
// W1T[k][c][h] f32 (recheck); W1b[h][kw*256+c] bf16 RNE; same for w2; v[h]=w3[1,h]-w3[0,h]
__global__ void repack_kernel(const float* __restrict__ w1, const float* __restrict__ w2,
                              const float* __restrict__ w3,
                              float* __restrict__ W1T, float* __restrict__ W2T,
                              float* __restrict__ v,
                              unsigned short* __restrict__ W1b, unsigned short* __restrict__ W2b)
{
    int idx = blockIdx.x * blockDim.x + threadIdx.x;
    int stride = gridDim.x * blockDim.x;
    for (int i = idx; i < KW * CDIM * HDIM; i += stride) {
        int k = i / (CDIM * HDIM), c = (i / HDIM) % CDIM, h = i % HDIM;
        W1T[i] = w1[(size_t)h * (CDIM * KW) + c * KW + k];
    }
    for (int i = idx; i < 3 * HDIM * HDIM; i += stride) {
        int k = i / (HDIM * HDIM), c = (i / HDIM) % HDIM, h = i % HDIM;
        W2T[i] = w2[(size_t)h * (HDIM * 3) + c * 3 + k];
    }
    for (int i = idx; i < HDIM * 1792; i += stride) {
        int h = i / 1792, kc = i % 1792, kw = kc >> 8, c = kc & 255;
        W1b[i] = bf16_rne(w1[(size_t)h * 1792 + c * 7 + kw]);
    }
    for (int i = idx; i < HDIM * 768; i += stride) {
        int h = i / 768, kc = i % 768, kw = kc >> 8, c = kc & 255;
        W2b[i] = bf16_rne(w2[(size_t)h * 768 + c * 3 + kw]);
    }
    if (idx < HDIM) v[idx] = w3[HDIM + idx] - w3[idx];
}

// ---------------- x -> bf16 (RNE) one-time cast ----------------
__global__ __launch_bounds__(256) void xcast_kernel(const float* __restrict__ x,
                                                    unsigned short* __restrict__ xbf)
{
    size_t i = ((size_t)blockIdx.x * 256 + threadIdx.x) * 8;
    float4 a = *(const float4*)(x + i);
    float4 b = *(const float4*)(x + i + 4);
    short8 o;
    o[0] = (short)bf16_rne(a.x); o[1] = (short)bf16_rne(a.y);
    o[2] = (short)bf16_rne(a.z); o[3] = (short)bf16_rne(a.w);
    o[4] = (short)bf16_rne(b.x); o[5] = (short)bf16_rne(b.y);
    o[6] = (short)bf16_rne(b.z); o[7] = (short)bf16_rne(b.w);
    *(short8*)(xbf + i) = o;
}

// ---------------- conv1: pure bf16 MFMA, all-DMA staging ----------------
// Block 256t x 128h, 4 waves of 64t x 128h. cc-chunks of 32 c; B staged 4 kw taps
// per phase (4 barriers/cc). A rows padded to stride 322 (322%8=2 -> bank spread),
// B n-stride 130 (130%8=2).
__global__ __launch_bounds__(256) void conv1_mfma(
    const unsigned short* __restrict__ xbf,
    const unsigned short* __restrict__ Wb,
    const float* __restrict__ b1,
    const unsigned short* __restrict__ zerobuf,
    unsigned short* __restrict__ h1)
{
    __shared__ short8 A8[4 * 322];       // [q][row], rows 0..261 valid (t = t0+row-3)
    __shared__ short8 B8[16 * 130];      // [kwslot][q][n]
    const int tid = threadIdx.x, lane = tid & 63, wid = tid >> 6;
    const int b  = blockIdx.x >> 5;
    const int t0 = (blockIdx.x & 31) << 8;
    const int h0 = blockIdx.y << 7;
    const int q = lane >> 4, l15 = lane & 15;
    const unsigned short* xb = xbf + (size_t)b * T * 256;

    f32x4 acc[4][8] = {};

    for (int cc = 0; cc < 8; ++cc) {
        const int c0 = cc << 5;
        __syncthreads();
        // A: 20 segs; wave wid handles q=wid, parts 0..4
        #pragma unroll
        for (int part = 0; part < 5; ++part) {
            int row = part * 64 + lane;
            int t = t0 + row - 3;
            const unsigned short* src = (row < 262 && t >= 0 && t < T)
                ? xb + (size_t)t * 256 + c0 + wid * 8 : zerobuf;
            gl_lds16(src, &A8[wid * 322 + part * 64]);
        }
        // B kw 0..3: wave wid stages kw=wid (8 segs: 4 q x 2 halves)
        #pragma unroll
        for (int s = 0; s < 8; ++s) {
            int bq = s >> 1, half = s & 1;
            const unsigned short* src = Wb + (size_t)(h0 + half * 64 + lane) * 1792
                                        + wid * 256 + c0 + bq * 8;
            gl_lds16(src, &B8[(wid * 4 + bq) * 130 + half * 64]);
        }
        __syncthreads();
        #pragma unroll
        for (int kw = 0; kw < 4; ++kw) {
            short8 ah[4], bh[8];
            const int rbase = wid * 64 + l15 + kw;
            #pragma unroll
            for (int i = 0; i < 4; ++i) ah[i] = A8[q * 322 + rbase + i * 16];
            #pragma unroll
            for (int j = 0; j < 8; ++j) bh[j] = B8[(kw * 4 + q) * 130 + j * 16 + l15];
            #pragma unroll
            for (int i = 0; i < 4; ++i)
                #pragma unroll
                for (int j = 0; j < 8; ++j)
                    acc[i][j] = __builtin_amdgcn_mfma_f32_16x16x32_bf16(ah[i], bh[j], acc[i][j], 0, 0, 0);
        }
        __syncthreads();
        // B kw 4..6: 24 segs, wave does 6
        #pragma unroll
        for (int s = 0; s < 6; ++s) {
            int seg = wid * 6 + s;
            int kw2 = seg >> 3, bq = (seg >> 1) & 3, half = seg & 1;
            const unsigned short* src = Wb + (size_t)(h0 + half * 64 + lane) * 1792
                                        + (kw2 + 4) * 256 + c0 + bq * 8;
            gl_lds16(src, &B8[(kw2 * 4 + bq) * 130 + half * 64]);
        }
        __syncthreads();
        #pragma unroll
        for (int kw = 4; kw < 7; ++kw) {
            short8 ah[4], bh[8];
            const int rbase = wid * 64 + l15 + kw;
            const int slot = kw - 4;
            #pragma unroll
            for (int i = 0; i < 4; ++i) ah[i] = A8[q * 322 + rbase + i * 16];
            #pragma unroll
            for (int j = 0; j < 8; ++j) bh[j] = B8[(slot * 4 + q) * 130 + j * 16 + l15];
            #pragma unroll
            for (int i = 0; i < 4; ++i)
                #pragma unroll
                for (int j = 0; j < 8; ++j)
                    acc[i][j] = __builtin_amdgcn_mfma_f32_16x16x32_bf16(ah[i], bh[j], acc[i][j], 0, 0, 0);
        }
    }
    // epilogue: bias+relu, store h1 bf16
    #pragma unroll
    for (int j = 0; j < 8; ++j) {
        int h = h0 + j * 16 + l15;
        float bb = b1[h];
        #pragma unroll
        for (int i = 0; i < 4; ++i) {
            int tb = t0 + wid * 64 + i * 16 + q * 4;
            #pragma unroll
            for (int r = 0; r < 4; ++r)
                h1[(size_t)(b * T + tb + r) * 256 + h] = bf16_rne(fmaxf(acc[i][j][r] + bb, 0.f));
        }
    }
}

// ---------------- conv2: pure bf16 MFMA + fused 1x1 score ----------------
__global__ __launch_bounds__(256) void conv2_mfma(
    const unsigned short* __restrict__ h1,
    const unsigned short* __restrict__ Wb,
    const float* __restrict__ b2, const float* __restrict__ v,
    const unsigned short* __restrict__ zerobuf,
    float* __restrict__ dlog)
{
    __shared__ short8 A8[4 * 322];       // rows 0..257 valid (t = t0+row-1)
    __shared__ short8 B8[12 * 130];      // 3 kw x 4 q x 130
    const int tid = threadIdx.x, lane = tid & 63, wid = tid >> 6;
    const int b  = blockIdx.x >> 5;
    const int t0 = (blockIdx.x & 31) << 8;
    const int h0 = blockIdx.y << 7;
    const int q = lane >> 4, l15 = lane & 15;
    const unsigned short* hb = h1 + (size_t)b * T * 256;

    f32x4 acc[4][8] = {};

    for (int cc = 0; cc < 8; ++cc) {
        const int c0 = cc << 5;
        __syncthreads();
        #pragma unroll
        for (int part = 0; part < 5; ++part) {
            int row = part * 64 + lane;
            int t = t0 + row - 1;
            const unsigned short* src = (row < 258 && t >= 0 && t < T)
                ? hb + (size_t)t * 256 + c0 + wid * 8 : zerobuf;
            gl_lds16(src, &A8[wid * 322 + part * 64]);
        }
        #pragma unroll
        for (int s = 0; s < 6; ++s) {
            int seg = wid * 6 + s;
            int kw = seg >> 3, bq = (seg >> 1) & 3, half = seg & 1;
            const unsigned short* src = Wb + (size_t)(h0 + half * 64 + lane) * 768
                                        + kw * 256 + c0 + bq * 8;
            gl_lds16(src, &B8[(kw * 4 + bq) * 130 + half * 64]);
        }
        __syncthreads();
        #pragma unroll
        for (int kw = 0; kw < 3; ++kw) {
            short8 ah[4], bh[8];
            const int rbase = wid * 64 + l15 + kw;
            #pragma unroll
            for (int i = 0; i < 4; ++i) ah[i] = A8[q * 322 + rbase + i * 16];
            #pragma unroll
            for (int j = 0; j < 8; ++j) bh[j] = B8[(kw * 4 + q) * 130 + j * 16 + l15];
            #pragma unroll
            for (int i = 0; i < 4; ++i)
                #pragma unroll
                for (int j = 0; j < 8; ++j)
                    acc[i][j] = __builtin_amdgcn_mfma_f32_16x16x32_bf16(ah[i], bh[j], acc[i][j], 0, 0, 0);
        }
    }
    // epilogue: p = sum_h v[h]*relu(h2+b2), reduce 16 lanes per quad, atomicAdd per token
    float vv[8], bb[8];
    #pragma unroll
    for (int j = 0; j < 8; ++j) {
        int h = h0 + j * 16 + l15;
        vv[j] = v[h]; bb[j] = b2[h];
    }
    #pragma unroll
    for (int i = 0; i < 4; ++i) {
        int tb = t0 + wid * 64 + i * 16 + q * 4;
        #pragma unroll
        for (int r = 0; r < 4; ++r) {
            float s = 0.f;
            #pragma unroll
            for (int j = 0; j < 8; ++j)
                s += fmaxf(acc[i][j][r] + bb[j], 0.f) * vv[j];
            #pragma unroll
            for (int m = 1; m < 16; m <<= 1)
                s += __shfl_xor(s, m, 64);
            if (l15 == 0) atomicAdd(&dlog[b * T + tb + r], s);
        }
    }
}

// ---------------- boundary bit + uncertainty list ----------------
__global__ void boundary_kernel(const float* __restrict__ d, const int* __restrict__ padmask,
                                const float* __restrict__ b3,
                                int* __restrict__ isb, int* __restrict__ ucount,
                                int* __restrict__ ulist)
{
    int bt = blockIdx.x * 256 + threadIdx.x;
    if (bt >= BT) return;
    int pad = padmask[bt];
    float dd = d[bt] + (b3[1] - b3[0]);
    isb[bt] = (pad == 0 && dd > 0.f) ? 1 : 0;
    if (pad == 0 && fabsf(dd) < TAU) {
        int slot = atomicAdd(ucount, 1);
        if (slot < UCAP) ulist[slot] = bt;
    }
}

// ---------------- exact f64 recheck of near-tie tokens ----------------
__global__ __launch_bounds__(256) void recheck_kernel(
    const float* __restrict__ x, const float* __restrict__ W1T,
    const float* __restrict__ W2T, const float* __restrict__ b1,
    const float* __restrict__ b2, const float* __restrict__ w3,
    const float* __restrict__ b3,
    const int* __restrict__ ulist, const int* __restrict__ ucount,
    int* __restrict__ isb)
{
    __shared__ double h1s[3][HDIM];
    __shared__ double red[HDIM];
    int n = *ucount; if (n > UCAP) n = UCAP;
    const int h = threadIdx.x;
    for (int li = blockIdx.x; li < n; li += gridDim.x) {
        int bt = ulist[li];
        int b = bt >> 13, t = bt & (T - 1);
        #pragma unroll
        for (int dt = -1; dt <= 1; ++dt) {
            double acc = (double)b1[h];
            int tc = t + dt;
            if (tc >= 0 && tc < T) {
                for (int k = 0; k < KW; ++k) {
                    int tt = tc + k - 3;
                    if (tt < 0 || tt >= T) continue;
                    const float* xrow = &x[(size_t)(b * T + tt) * CDIM];
                    const float* wrow = &W1T[(size_t)k * 65536 + h];
                    for (int c = 0; c < CDIM; ++c)
                        acc += (double)xrow[c] * (double)wrow[(size_t)c * 256];
                }
            }
            h1s[dt + 1][h] = acc > 0.0 ? acc : 0.0;
        }
        __syncthreads();
        double acc2 = (double)b2[h];
        for (int k = 0; k < 3; ++k) {
            int tt = t + k - 1;
            if (tt < 0 || tt >= T) continue;
            const double* hrow = h1s[k];
            const float* wrow = &W2T[(size_t)k * 65536 + h];
            for (int c = 0; c < HDIM; ++c)
                acc2 += hrow[c] * (double)wrow[(size_t)c * 256];
        }
        double h2v = acc2 > 0.0 ? acc2 : 0.0;
        double vd = (double)w3[HDIM + h] - (double)w3[h];
        red[h] = vd * h2v;
        __syncthreads();
        for (int off = 128; off > 0; off >>= 1) {
            if (h < off) red[h] += red[h + off];
            __syncthreads();
        }
        if (h == 0) {
            double dd = red[0] + ((double)b3[1] - (double)b3[0]);
            isb[bt] = (dd > 0.0) ? 1 : 0;
        }
        __syncthreads();
    }
}

// ---------------- per-batch inclusive cumsum -> seg_id, n_valid ----------------
__global__ __launch_bounds__(1024) void scan_kernel(
    const int* __restrict__ isb, const int* __restrict__ padmask,
    int* __restrict__ sid, int* __restrict__ nvalid)
{
    __shared__ int ssum[1024];
    const int b = blockIdx.x, tid = threadIdx.x;
    const int base = b * T;
    int vals[8]; int s = 0;
    #pragma unroll
    for (int i = 0; i < 8; ++i) { vals[i] = isb[base + tid * 8 + i]; s += vals[i]; }
    ssum[tid] = s;
    __syncthreads();
    for (int off = 1; off < 1024; off <<= 1) {
        int add = (tid >= off) ? ssum[tid - off] : 0;
        __syncthreads();
        ssum[tid] += add;
        __syncthreads();
    }
    int run = ssum[tid] - s;
    #pragma unroll
    for (int i = 0; i < 8; ++i) {
        int t = tid * 8 + i;
        run += vals[i];
        sid[base + t] = (padmask[base + t] != 0) ? T : run;
    }
    if (tid == 1023) {
        int nb = ssum[1023];
        nvalid[b] = (padmask[base] == 0) ? (nb + 1) : 0;
    }
}

// ---------------- segment range extraction ----------------
__global__ void segbounds_kernel(const int* __restrict__ sid, const int* __restrict__ padmask,
                                 int* __restrict__ sst, int* __restrict__ sen)
{
    int bt = blockIdx.x * 256 + threadIdx.x;
    if (bt >= BT) return;
    if (padmask[bt] != 0) return;
    int t = bt & (T - 1);
    int b = bt >> 13;
    int s = sid[bt];
    if (t == 0) {
        if (s < T) sst[b * T + s] = 0;
    } else if (s != sid[bt - 1]) {
        if (s < T) sst[b * T + s] = t;
    }
    bool last = (t == T - 1) || (padmask[bt + 1] != 0);
    if (s < T && (last || sid[bt + 1] != s)) sen[b * T + s] = t + 1;
}

// ---------------- segment-mean pooling + new_pad ----------------
__global__ __launch_bounds__(256) void pool_kernel(
    const float* __restrict__ x, const int* __restrict__ sst,
    const int* __restrict__ sen, const int* __restrict__ nvalid,
    float* __restrict__ out)
{
    int slot = blockIdx.x * 4 + (threadIdx.x >> 6);
    int lane = threadIdx.x & 63;
    int b = slot >> 13;
    int s = slot & (T - 1);
    int nv = nvalid[b];
    float4 res = make_float4(0.f, 0.f, 0.f, 0.f);
    if (s < nv) {
        int st = sst[slot], en = sen[slot];
        if (st >= 0 && en > st) {
            float4 a = make_float4(0.f, 0.f, 0.f, 0.f);
            const float* xp = &x[(size_t)(b * T + st) * CDIM + lane * 4];
            for (int t = st; t < en; ++t) {
                float4 xv = *(const float4*)xp;
                a.x += xv.x; a.y += xv.y; a.z += xv.z; a.w += xv.w;
                xp += CDIM;
            }
            float inv = 1.f / (float)(en - st);
            res = make_float4(a.x * inv, a.y * inv, a.z * inv, a.w * inv);
        }
    }
    *(float4*)&out[(size_t)slot * CDIM + lane * 4] = res;
    if (lane == 0) out[(size_t)BT * CDIM + slot] = (s < nv) ? 0.f : 1.f;
}

extern "C" void kernel_launch(void* const* d_in, const int* in_sizes, int n_in,
                              void* d_out, int out_size, void* d_ws, size_t ws_size,
                              hipStream_t stream)
{
    const float* x  = (const float*)d_in[0];
    const int* padmask = (const int*)d_in[1];
    const float* w1 = (const float*)d_in[2];
    const float* b1 = (const float*)d_in[3];
    const float* w2 = (const float*)d_in[4];
    const float* b2 = (const float*)d_in[5];
    const float* w3 = (const float*)d_in[6];
    const float* b3 = (const float*)d_in[7];

    char* ws = (char*)d_ws;
    float* W1T = (float*)(ws + B_W1T);
    float* W2T = (float*)(ws + B_W2T);
    float* v   = (float*)(ws + B_V);
    float* dlog = (float*)(ws + B_D);
    int* isb = (int*)(ws + B_ISB);
    int* sid = (int*)(ws + B_SID);
    int* sst = (int*)(ws + B_SST);
    int* sen = (int*)(ws + B_SEN);
    int* nv  = (int*)(ws + B_NV);
    int* uct = (int*)(ws + B_UCT);
    int* ul  = (int*)(ws + B_UL);
    unsigned short* zerobuf = (unsigned short*)(ws + B_ZERO);
    unsigned short* W1b = (unsigned short*)(ws + B_W1B);
    unsigned short* W2b = (unsigned short*)(ws + B_W2B);

    float* out = (float*)d_out;
    // d_out scratch: h1 bf16 [BT][256] in the first half of new_logits, xbf bf16 [BT][256] in the second
    unsigned short* h1  = (unsigned short*)out;
    unsigned short* xbf = h1 + (size_t)BT * 256;

    hipMemsetAsync(dlog, 0, BT * sizeof(float), stream);
    hipMemsetAsync(sst, 0xFF, BT * sizeof(int), stream);
    hipMemsetAsync(sen, 0xFF, BT * sizeof(int), stream);
    hipMemsetAsync(uct, 0, sizeof(int), stream);
    hipMemsetAsync(zerobuf, 0, 256, stream);

    repack_kernel<<<1024, 256, 0, stream>>>(w1, w2, w3, W1T, W2T, v, W1b, W2b);
    xcast_kernel<<<BT * 256 / (8 * 256), 256, 0, stream>>>(x, xbf);
    conv1_mfma<<<dim3(BSZ * (T / 256), HDIM / 128), 256, 0, stream>>>(
        xbf, W1b, b1, zerobuf, h1);
    conv2_mfma<<<dim3(BSZ * (T / 256), HDIM / 128), 256, 0, stream>>>(
        h1, W2b, b2, v, zerobuf, dlog);
    boundary_kernel<<<BT / 256, 256, 0, stream>>>(dlog, padmask, b3, isb, uct, ul);
    recheck_kernel<<<2048, 256, 0, stream>>>(x, W1T, W2T, b1, b2, w3, b3, ul, uct, isb);
    scan_kernel<<<BSZ, 1024, 0, stream>>>(isb, padmask, sid, nv);
    segbounds_kernel<<<BT / 256, 256, 0, stream>>>(sid, padmask, sst, sen);
    pool_kernel<<<BT / 4, 256, 0, stream>>>(x, sst, sen, nv, out);
}